// Round 1
// 375.918 us; speedup vs baseline: 1.0442x; 1.0442x over previous
//
#include <hip/hip_runtime.h>

// Problem constants (B,T,D,H from reference)
#define B_  4
#define T_  2048
#define D_  1024
#define H_  16
#define HD_ 64
#define BT_ (B_*T_)   // 8192
#define K_  D_        // 1024 (GEMM inner dim)

typedef unsigned short u16;
typedef unsigned int   u32;

typedef __attribute__((ext_vector_type(8))) short bf16x8;  // 8 bf16 (4 VGPRs)
typedef __attribute__((ext_vector_type(4))) float f32x4;   // MFMA 16x16 C/D

__device__ __forceinline__ u16 f2bf(float f) {
  u32 u = __builtin_bit_cast(u32, f);
  u += 0x7fffu + ((u >> 16) & 1u);   // round-to-nearest-even
  return (u16)(u >> 16);
}

__device__ __forceinline__ u32 pack2bf(float a, float b) {
  u32 ua = __builtin_bit_cast(u32, a) + 0x8000u;
  u32 ub = __builtin_bit_cast(u32, b) + 0x8000u;
  return (ub & 0xFFFF0000u) | (ua >> 16);
}

#define GLOAD_LDS16(g, l) __builtin_amdgcn_global_load_lds(                  \
    (const __attribute__((address_space(1))) void*)(g),                      \
    (__attribute__((address_space(3))) void*)(l), 16, 0, 0)

// compiler-only memory barrier: forbids IR reordering of LDS/global ops
#define MEMBAR() __asm__ volatile("" ::: "memory")

#define SFC 0.18033688011f   /* 0.125 * log2(e); folded into Q projection */

// ---------------- fp32 -> bf16 elementwise convert (float4 -> 8B) -------------
__global__ __launch_bounds__(256) void cvt_f32_bf16(
    const float* __restrict__ in, u16* __restrict__ out, int n4) {
  int i = blockIdx.x * 256 + threadIdx.x;
  if (i >= n4) return;
  float4 x = ((const float4*)in)[i];
  u32 lo = (u32)f2bf(x.x) | ((u32)f2bf(x.y) << 16);
  u32 hi = (u32)f2bf(x.z) | ((u32)f2bf(x.w) << 16);
  ((uint2*)out)[i] = make_uint2(lo, hi);
}

// ---------------- GEMM: 128x128 tile (m97 template; grid 512) -----------------
// Out[m,n] = (A[m,:]·W[n,:] + bias[n]) * oscale.  4 waves 2x2 (each 64x64),
// BK=32, global_load_lds w16 (2 issues A + 2 issues B).  Slot-swizzle
// (slot ^= row&3) kills the 64B power-of-2 row-stride conflicts on frag reads.
template<bool OUT_BF16>
__global__ __launch_bounds__(256) void gemm_xwt_lds(
    const u16* __restrict__ A, const u16* __restrict__ W,
    const float* __restrict__ bias, void* __restrict__ Out,
    int M, int N, int K, float oscale)
{
  __shared__ u16 As[128 * 32];   // [row][slot'][8], slot' = kseg ^ (row&3)
  __shared__ u16 Bs[128 * 32];

  const int tid  = threadIdx.x;
  const int wave = tid >> 6;
  const int lane = tid & 63;
  const int col  = lane & 15;
  const int quad = lane >> 4;
  const int wy   = wave >> 1;          // m-half (64)
  const int wx   = wave & 1;           // n-half (64)
  const int tiles_n = N >> 7;
  const int m0 = (blockIdx.x / tiles_n) * 128;
  const int n0 = (blockIdx.x % tiles_n) * 128;

  // staging: 4 threads per row (64 rows/issue), source k-seg swizzled by row&3
  const int srow = tid >> 2;                         // 0..63
  const int sseg = ((tid & 3) ^ (srow & 3)) * 8;     // row+64 keeps row&3
  const u16* agp = A + (size_t)(m0 + srow) * K + sseg;
  const u16* bgp = W + (size_t)(n0 + srow) * K + sseg;
  u16* const alds = As + tid * 8;
  u16* const blds = Bs + tid * 8;

  f32x4 acc[4][4];
  const f32x4 z = {0.f, 0.f, 0.f, 0.f};
#pragma unroll
  for (int i = 0; i < 4; ++i)
#pragma unroll
    for (int j = 0; j < 4; ++j) acc[i][j] = z;

  // fragment LDS offsets: row*32 + (quad ^ (row&3))*8 ; row&3 == col&3
  const int rslot = (quad ^ (col & 3)) * 8;
  u32 aro[4], bro[4];
#pragma unroll
  for (int i = 0; i < 4; ++i)
    aro[i] = (u32)((wy*64 + i*16 + col) * 32 + rslot);
#pragma unroll
  for (int i = 0; i < 4; ++i)
    bro[i] = (u32)((wx*64 + i*16 + col) * 32 + rslot);

  for (int k0 = 0; k0 < K; k0 += 32) {
    GLOAD_LDS16(agp + k0,          alds);            // A rows 0..63
    GLOAD_LDS16(agp + k0 + 64 * K, alds + 2048);     // A rows 64..127
    GLOAD_LDS16(bgp + k0,          blds);            // B rows 0..63
    GLOAD_LDS16(bgp + k0 + 64 * K, blds + 2048);     // B rows 64..127
    __syncthreads();

    bf16x8 af[4], bf[4];
#pragma unroll
    for (int i = 0; i < 4; ++i) af[i] = *(const bf16x8*)(As + aro[i]);
#pragma unroll
    for (int i = 0; i < 4; ++i) bf[i] = *(const bf16x8*)(Bs + bro[i]);
#pragma unroll
    for (int mt = 0; mt < 4; ++mt)
#pragma unroll
      for (int nt = 0; nt < 4; ++nt)
        acc[mt][nt] = __builtin_amdgcn_mfma_f32_16x16x32_bf16(
            af[mt], bf[nt], acc[mt][nt], 0, 0, 0);
    __syncthreads();
  }

#pragma unroll
  for (int nt = 0; nt < 4; ++nt) {
    const int n = n0 + wx*64 + nt*16 + col;
    const float bv = bias[n];
#pragma unroll
    for (int mt = 0; mt < 4; ++mt) {
#pragma unroll
      for (int r = 0; r < 4; ++r) {
        const int m = m0 + wy*64 + mt*16 + quad*4 + r;
        const float v = (acc[mt][nt][r] + bv) * oscale;
        if (OUT_BF16) ((u16*)Out)[(size_t)m * N + n] = f2bf(v);
        else          ((float*)Out)[(size_t)m * N + n] = v;
      }
    }
  }
}

// ---------------- V transpose: Vp[b,t,h,hd] -> Vt[b,h,hd,t] -------------------
__global__ __launch_bounds__(256) void transpose_v(
    const u16* __restrict__ Vp, u16* __restrict__ Vt) {
  const int blk = blockIdx.x;
  const int tt = blk & 31;
  const int bh = blk >> 5;
  const int b = bh >> 4, h = bh & 15;
  const int t0 = tt * 64;
  __shared__ u16 tile[64][66];
#pragma unroll
  for (int pass = 0; pass < 16; ++pass) {
    const int t = (threadIdx.x >> 6) + pass*4;
    const int d = threadIdx.x & 63;
    tile[t][d] = Vp[(size_t)(b*T_ + t0 + t) * D_ + h*HD_ + d];
  }
  __syncthreads();
#pragma unroll
  for (int pass = 0; pass < 16; ++pass) {
    const int d = (threadIdx.x >> 6) + pass*4;
    const int t = threadIdx.x & 63;
    Vt[(size_t)(bh*HD_ + d) * T_ + t0 + t] = tile[t][d];
  }
}

// ---------------- Flash attention: dbuf-staged K/V, 128-row q-blocks ----------
// Block = (bh, 128-row q-tile), grid 1024 dispatched longest-first.  Each wave
// owns TWO 16-row q-groups (rows wave*16 and 64+wave*16) so every staged K/V
// tile feeds 32 MFMAs/wave (K/V frag reads shared between groups).  K/V tiles
// are DOUBLE-BUFFERED: tile t+1's global_load_lds issues before tile t's
// compute, so the vmcnt(0) drain at the end-of-iteration __syncthreads waits on
// loads that aged a whole compute phase (T14 issue-early/drain-late).  One
// barrier per tile.  Softmax fixed-max (Q pre-scaled to log2 units).
__global__ __launch_bounds__(256) void attn_fwd(
    const u16* __restrict__ Qp, const u16* __restrict__ Kp,
    const u16* __restrict__ Vt, u16* __restrict__ Oout)
{
  __shared__ u16 Ks[2 * 4096];  // [buf][slot=hd/8][row=j][8]
  __shared__ u16 Vs[2 * 4096];  // [buf][slot=t/8][row=hd][8]
  __shared__ __align__(16) u16 plds[4 * 32 * 72];   // per-wave P, stride 72

  const int tid  = threadIdx.x;
  const int wave = tid >> 6;
  const int lane = tid & 63;
  const int col  = lane & 15;
  const int quad = lane >> 4;
  const int blk  = blockIdx.x;
  const int bh   = blk & 63;
  const int qt   = 15 - (blk >> 6);   // longest blocks first
  const int b = bh >> 4, h = bh & 15;
  const int rb0 = qt*128 + wave*16;   // group0 rows
  const int rb1 = rb0 + 64;           // group1 rows
  const int q0 = rb0 + col;
  const int q1 = rb1 + col;

  u16* const pl = plds + wave * 32 * 72;   // rows 0..15 grp0, 16..31 grp1

  // Q fragments (B-operand rows, k-contig; pre-scaled by SFC)
  bf16x8 qa0, qa1, qb0, qb1;
  {
    const u16* qr = Qp + (size_t)(b*T_ + q0) * D_ + h*HD_ + quad*8;
    qa0 = *(const bf16x8*)(qr);
    qa1 = *(const bf16x8*)(qr + 32);
    qr += (size_t)64 * D_;
    qb0 = *(const bf16x8*)(qr);
    qb1 = *(const bf16x8*)(qr + 32);
  }

  const u16* kbase = Kp + (size_t)(b*T_) * D_ + h*HD_;
  const u16* vbase = Vt + (size_t)(bh*HD_) * T_;

  // staging source maps (16B per thread per issue; slot = lin>>6, row = lin&63)
  const int srow  = tid & 63;
  const int sslot = tid >> 6;          // 0..3 (second issue adds +4)
  const u16* kg0 = kbase + (size_t)srow * D_ + sslot*8;        // + j0*D
  const u16* kg1 = kbase + (size_t)srow * D_ + (4+sslot)*8;
  const u16* vg0 = vbase + (size_t)srow * T_ + sslot*8;        // + j0
  const u16* vg1 = vbase + (size_t)srow * T_ + (4+sslot)*8;

  const f32x4 z = {0.f, 0.f, 0.f, 0.f};
  f32x4 oa[4], ob[4];
#pragma unroll
  for (int dt = 0; dt < 4; ++dt) { oa[dt] = z; ob[dt] = z; }
  f32x4 la = z, lb = z;

  const int jend0  = qt * 128;        // group0 diagonal tile start
  const int jend1  = qt * 128 + 64;   // group1 diagonal tile start (last tile)
  const int ntiles = (jend1 >> 6) + 1;

  // prologue: stage tile 0 -> buf 0, full drain once
  GLOAD_LDS16(kg0, Ks + tid*8);
  GLOAD_LDS16(kg1, Ks + 2048 + tid*8);
  GLOAD_LDS16(vg0, Vs + tid*8);
  GLOAD_LDS16(vg1, Vs + 2048 + tid*8);
  __syncthreads();

  int cur = 0;
  for (int t = 0; t < ntiles; ++t) {
    const int j0 = t << 6;

    // ---- issue tile t+1's staging into the other buffer (latency hides
    //      under this tile's compute; drained by the end-of-iter barrier) ----
    if (t + 1 < ntiles) {
      const int jn = j0 + 64;
      const size_t kj = (size_t)jn * D_;
      u16* kb = Ks + (cur ^ 1) * 4096;
      u16* vb = Vs + (cur ^ 1) * 4096;
      GLOAD_LDS16(kg0 + kj, kb + tid*8);
      GLOAD_LDS16(kg1 + kj, kb + 2048 + tid*8);
      GLOAD_LDS16(vg0 + jn, vb + tid*8);
      GLOAD_LDS16(vg1 + jn, vb + 2048 + tid*8);
    }
    MEMBAR();   // pin the issue point: don't sink loads into/past compute

    const u16* kr = Ks + cur * 4096;
    const u16* vr = Vs + cur * 4096;

    // ---- S^T = K Q^T for both q-groups (K frags shared) --------------------
    f32x4 sa[4], sb[4];
    __builtin_amdgcn_s_setprio(1);
#pragma unroll
    for (int jt = 0; jt < 4; ++jt) {
      bf16x8 kf0 = *(const bf16x8*)(kr + (quad*64 + jt*16 + col) * 8);
      bf16x8 kf1 = *(const bf16x8*)(kr + 2048 + (quad*64 + jt*16 + col) * 8);
      sa[jt] = __builtin_amdgcn_mfma_f32_16x16x32_bf16(kf0, qa0, z, 0,0,0);
      sa[jt] = __builtin_amdgcn_mfma_f32_16x16x32_bf16(kf1, qa1, sa[jt], 0,0,0);
      sb[jt] = __builtin_amdgcn_mfma_f32_16x16x32_bf16(kf0, qb0, z, 0,0,0);
      sb[jt] = __builtin_amdgcn_mfma_f32_16x16x32_bf16(kf1, qb1, sb[jt], 0,0,0);
    }
    __builtin_amdgcn_s_setprio(0);

    // ---- fixed-max softmax (scores already in log2 units) ------------------
    // group0: full mask when j0 >= jend0 (covers diagonal AND the last tile
    // where group0 is entirely above the diagonal -> contributes zeros)
    if (j0 >= jend0) {
      const int dq = q0 - j0;
#pragma unroll
      for (int jt = 0; jt < 4; ++jt)
#pragma unroll
        for (int r = 0; r < 4; ++r) {
          const int jo = jt*16 + quad*4 + r;
          sa[jt][r] = (jo > dq) ? 0.f : __builtin_amdgcn_exp2f(sa[jt][r]);
        }
    } else {
#pragma unroll
      for (int jt = 0; jt < 4; ++jt)
#pragma unroll
        for (int r = 0; r < 4; ++r)
          sa[jt][r] = __builtin_amdgcn_exp2f(sa[jt][r]);
    }
    if (j0 >= jend1) {                 // group1 diagonal (last tile only)
      const int dq = q1 - j0;
#pragma unroll
      for (int jt = 0; jt < 4; ++jt)
#pragma unroll
        for (int r = 0; r < 4; ++r) {
          const int jo = jt*16 + quad*4 + r;
          sb[jt][r] = (jo > dq) ? 0.f : __builtin_amdgcn_exp2f(sb[jt][r]);
        }
    } else {
#pragma unroll
      for (int jt = 0; jt < 4; ++jt)
#pragma unroll
        for (int r = 0; r < 4; ++r)
          sb[jt][r] = __builtin_amdgcn_exp2f(sb[jt][r]);
    }
#pragma unroll
    for (int jt = 0; jt < 4; ++jt) { la += sa[jt]; lb += sb[jt]; }

    // ---- P -> wave-private LDS (stride 72) ---------------------------------
    {
      u16* prow = pl + col * 72;
#pragma unroll
      for (int jt = 0; jt < 4; ++jt) {
        uint2 w2;
        w2.x = pack2bf(sa[jt][0], sa[jt][1]);
        w2.y = pack2bf(sa[jt][2], sa[jt][3]);
        *(uint2*)(prow + jt*16 + quad*4) = w2;
      }
      prow = pl + (16 + col) * 72;
#pragma unroll
      for (int jt = 0; jt < 4; ++jt) {
        uint2 w2;
        w2.x = pack2bf(sb[jt][0], sb[jt][1]);
        w2.y = pack2bf(sb[jt][2], sb[jt][3]);
        *(uint2*)(prow + jt*16 + quad*4) = w2;
      }
    }
    MEMBAR();   // cross-lane RAW through pl: forbid compiler reordering

    // ---- O^T += V^T P (V frags shared between groups) ----------------------
    {
      bf16x8 pa0 = *(const bf16x8*)(pl + col*72 + quad*8);
      bf16x8 pa1 = *(const bf16x8*)(pl + col*72 + 32 + quad*8);
      bf16x8 pb0 = *(const bf16x8*)(pl + (16+col)*72 + quad*8);
      bf16x8 pb1 = *(const bf16x8*)(pl + (16+col)*72 + 32 + quad*8);
      __builtin_amdgcn_s_setprio(1);
#pragma unroll
      for (int dt = 0; dt < 4; ++dt) {
        bf16x8 v0 = *(const bf16x8*)(vr + (quad*64 + dt*16 + col) * 8);
        bf16x8 v1 = *(const bf16x8*)(vr + 2048 + (quad*64 + dt*16 + col) * 8);
        oa[dt] = __builtin_amdgcn_mfma_f32_16x16x32_bf16(v0, pa0, oa[dt], 0,0,0);
        oa[dt] = __builtin_amdgcn_mfma_f32_16x16x32_bf16(v1, pa1, oa[dt], 0,0,0);
        ob[dt] = __builtin_amdgcn_mfma_f32_16x16x32_bf16(v0, pb0, ob[dt], 0,0,0);
        ob[dt] = __builtin_amdgcn_mfma_f32_16x16x32_bf16(v1, pb1, ob[dt], 0,0,0);
      }
      __builtin_amdgcn_s_setprio(0);
    }

    // end-of-tile barrier: drains tile t+1's loads (aged) + protects buffers
    __syncthreads();
    cur ^= 1;
  }

  // ---- epilogue: reduce l across quads, normalize, store --------------------
  float l0 = (la[0] + la[1]) + (la[2] + la[3]);
  l0 += __shfl_xor(l0, 16);
  l0 += __shfl_xor(l0, 32);
  const float ra = __builtin_amdgcn_rcpf(l0);
  float l1 = (lb[0] + lb[1]) + (lb[2] + lb[3]);
  l1 += __shfl_xor(l1, 16);
  l1 += __shfl_xor(l1, 32);
  const float rb = __builtin_amdgcn_rcpf(l1);

  u16* orow = Oout + (size_t)(b*T_ + q0) * D_ + h*HD_;
#pragma unroll
  for (int dt = 0; dt < 4; ++dt) {
    uint2 w2;
    w2.x = pack2bf(oa[dt][0]*ra, oa[dt][1]*ra);
    w2.y = pack2bf(oa[dt][2]*ra, oa[dt][3]*ra);
    *(uint2*)(orow + dt*16 + quad*4) = w2;
  }
  orow += (size_t)64 * D_;
#pragma unroll
  for (int dt = 0; dt < 4; ++dt) {
    uint2 w2;
    w2.x = pack2bf(ob[dt][0]*rb, ob[dt][1]*rb);
    w2.y = pack2bf(ob[dt][2]*rb, ob[dt][3]*rb);
    *(uint2*)(orow + dt*16 + quad*4) = w2;
  }
}

// ------------------------------- launcher -------------------------------------
extern "C" void kernel_launch(void* const* d_in, const int* in_sizes, int n_in,
                              void* d_out, int out_size, void* d_ws, size_t ws_size,
                              hipStream_t stream) {
  const float* q  = (const float*)d_in[0];
  const float* k  = (const float*)d_in[1];
  const float* v  = (const float*)d_in[2];
  // d_in[3] = mask: causal tril, implemented analytically
  const float* Wq = (const float*)d_in[4];
  const float* bq = (const float*)d_in[5];
  const float* Wk = (const float*)d_in[6];
  const float* bk = (const float*)d_in[7];
  const float* Wv = (const float*)d_in[8];
  const float* bv = (const float*)d_in[9];
  const float* Wo = (const float*)d_in[10];
  const float* bo = (const float*)d_in[11];
  float* out = (float*)d_out;

  char* w = (char*)d_ws;
  const size_t SZ = (size_t)BT_ * D_ * sizeof(u16);   // 16 MiB per tensor
  u16* Qp = (u16*)(w + 0*SZ);
  u16* Kp = (u16*)(w + 1*SZ);
  u16* Vp = (u16*)(w + 2*SZ);
  u16* Vt = (u16*)(w + 3*SZ);
  u16* Xb = (u16*)(w + 4*SZ);   // bf16 input scratch; later attention output
  u16* Wb = (u16*)(w + 5*SZ);   // bf16 weight scratch (2 MiB)

  const int n4x = BT_ * D_ / 4;
  const int n4w = D_ * D_ / 4;
  const int cvx = n4x / 256, cvw = n4w / 256;
  const int gemm_g = (BT_/128) * (D_/128);       // 512 blocks (2/CU)
  const int tr_g   = (B_*H_) * (T_/64);          // 2048 blocks
  const int attn_g = (B_*H_) * (T_/128);         // 1024 blocks, longest-first
  dim3 blk(256);

  // Q projection (pre-scaled by SFC so attention scores exit in log2 units)
  cvt_f32_bf16<<<cvx, blk, 0, stream>>>(q,  Xb, n4x);
  cvt_f32_bf16<<<cvw, blk, 0, stream>>>(Wq, Wb, n4w);
  gemm_xwt_lds<true><<<gemm_g, blk, 0, stream>>>(Xb, Wb, bq, Qp, BT_, D_, K_, SFC);
  // K projection
  cvt_f32_bf16<<<cvx, blk, 0, stream>>>(k,  Xb, n4x);
  cvt_f32_bf16<<<cvw, blk, 0, stream>>>(Wk, Wb, n4w);
  gemm_xwt_lds<true><<<gemm_g, blk, 0, stream>>>(Xb, Wb, bk, Kp, BT_, D_, K_, 1.0f);
  // V projection
  cvt_f32_bf16<<<cvx, blk, 0, stream>>>(v,  Xb, n4x);
  cvt_f32_bf16<<<cvw, blk, 0, stream>>>(Wv, Wb, n4w);
  gemm_xwt_lds<true><<<gemm_g, blk, 0, stream>>>(Xb, Wb, bv, Vp, BT_, D_, K_, 1.0f);
  // V transpose for PV operand layout
  transpose_v<<<tr_g, blk, 0, stream>>>(Vp, Vt);
  // attention (writes Xb)
  attn_fwd<<<attn_g, blk, 0, stream>>>(Qp, Kp, Vt, Xb);
  // output projection -> fp32 d_out
  cvt_f32_bf16<<<cvw, blk, 0, stream>>>(Wo, Wb, n4w);
  gemm_xwt_lds<false><<<gemm_g, blk, 0, stream>>>(Xb, Wb, bo, (void*)out, BT_, D_, K_, 1.0f);
}

// Round 2
// 344.400 us; speedup vs baseline: 1.1397x; 1.0915x over previous
//
#include <hip/hip_runtime.h>

// Problem constants (B,T,D,H from reference)
#define B_  4
#define T_  2048
#define D_  1024
#define H_  16
#define HD_ 64
#define BT_ (B_*T_)   // 8192
#define K_  D_        // 1024 (GEMM inner dim)

typedef unsigned short u16;
typedef unsigned int   u32;

typedef __attribute__((ext_vector_type(8))) short bf16x8;  // 8 bf16 (4 VGPRs)
typedef __attribute__((ext_vector_type(4))) float f32x4;   // MFMA 16x16 C/D

__device__ __forceinline__ u16 f2bf(float f) {
  u32 u = __builtin_bit_cast(u32, f);
  u += 0x7fffu + ((u >> 16) & 1u);   // round-to-nearest-even
  return (u16)(u >> 16);
}

__device__ __forceinline__ u32 pack2bf(float a, float b) {
  u32 ua = __builtin_bit_cast(u32, a) + 0x8000u;
  u32 ub = __builtin_bit_cast(u32, b) + 0x8000u;
  return (ub & 0xFFFF0000u) | (ua >> 16);
}

#define GLOAD_LDS16(g, l) __builtin_amdgcn_global_load_lds(                  \
    (const __attribute__((address_space(1))) void*)(g),                      \
    (__attribute__((address_space(3))) void*)(l), 16, 0, 0)

// compiler-only memory barrier: forbids IR reordering of LDS/global ops
#define MEMBAR() __asm__ volatile("" ::: "memory")

#define SFC 0.18033688011f   /* 0.125 * log2(e); folded into Q projection */

// ---------------- fp32 -> bf16 elementwise convert (float4 -> 8B) -------------
__global__ __launch_bounds__(256) void cvt_f32_bf16(
    const float* __restrict__ in, u16* __restrict__ out, int n4) {
  int i = blockIdx.x * 256 + threadIdx.x;
  if (i >= n4) return;
  float4 x = ((const float4*)in)[i];
  u32 lo = (u32)f2bf(x.x) | ((u32)f2bf(x.y) << 16);
  u32 hi = (u32)f2bf(x.z) | ((u32)f2bf(x.w) << 16);
  ((uint2*)out)[i] = make_uint2(lo, hi);
}

// ---------------- GEMM: 128x128 tile, BK=64, double-buffered ------------------
// Out[m,n] = (A[m,:]·W[n,:] + bias[n]) * oscale.  4 waves 2x2 (each 64x64).
// 2-phase pipeline: STAGE(t+1) issues BEFORE compute(t); the end-of-step
// __syncthreads (vmcnt(0) drain) then waits on loads that aged through
// 16 ds_read_b128 + 32 MFMA of compute.  One barrier per K-step.
// LDS rows are 128B -> 8-slot XOR swizzle (slot' = kseg ^ (row&7)) makes frag
// ds_read_b128 uniform 8 lanes/16B-slot (conflict-free); staging source is
// pre-swizzled per-lane so the linear global_load_lds dest matches (rule 21).
// Block swizzle clusters all n-tiles of 8 m-panels on one XCD: A panels stay
// L2-resident (4 MiB footprint per XCD = A 2 MiB + W 2 MiB).
template<bool OUT_BF16>
__global__ __launch_bounds__(256) void gemm_xwt_db(
    const u16* __restrict__ A, const u16* __restrict__ W,
    const float* __restrict__ bias, void* __restrict__ Out,
    int M, int N, int K, float oscale)
{
  __shared__ u16 As[2][128 * 64];   // [buf][row][slot'][8]
  __shared__ u16 Bs[2][128 * 64];

  const int tid  = threadIdx.x;
  const int wave = tid >> 6;
  const int lane = tid & 63;
  const int col  = lane & 15;
  const int quad = lane >> 4;
  const int wy   = wave >> 1;          // m-half (64)
  const int wx   = wave & 1;           // n-half (64)

  // XCD-clustered swizzle (requires gridDim.x % 8 == 0; here 512)
  const int tiles_n = N >> 7;                    // 8
  const int cpx     = (int)gridDim.x >> 3;       // 64 blocks per XCD
  const int mchunk  = cpx / tiles_n;             // 8 m-tiles per XCD
  const int xcd = blockIdx.x & 7;
  const int jj  = blockIdx.x >> 3;
  const int m0 = (xcd * mchunk + (jj % mchunk)) * 128;
  const int n0 = (jj / mchunk) * 128;

  // staging source map: issue covers 32 rows x 64 cols (4KB).
  // LDS linear dest t*16B == [row = 32i + t>>3][slot' = t&7]; global kseg must
  // satisfy kseg = slot' ^ (row&7).
  const int r5   = tid >> 3;                     // 0..31
  const int kseg = ((tid & 7) ^ (r5 & 7)) * 8;
  const u16* agp = A + (size_t)(m0 + r5) * K + kseg;
  const u16* bgp = W + (size_t)(n0 + r5) * K + kseg;

  f32x4 acc[4][4];
  const f32x4 z = {0.f, 0.f, 0.f, 0.f};
#pragma unroll
  for (int i = 0; i < 4; ++i)
#pragma unroll
    for (int jn = 0; jn < 4; ++jn) acc[i][jn] = z;

  // frag LDS offsets (u16 units): row*64 + ((kk*4+quad) ^ (row&7))*8
  u32 aro[4][2], bro[4][2];
#pragma unroll
  for (int i = 0; i < 4; ++i) {
    const int ar = wy*64 + i*16 + col;
    const int br = wx*64 + i*16 + col;
#pragma unroll
    for (int kk = 0; kk < 2; ++kk) {
      aro[i][kk] = (u32)(ar*64 + (((kk*4 + quad) ^ (ar & 7)) * 8));
      bro[i][kk] = (u32)(br*64 + (((kk*4 + quad) ^ (br & 7)) * 8));
    }
  }

  auto STAGE = [&](int buf, int k0) {
#pragma unroll
    for (int i = 0; i < 4; ++i) {
      GLOAD_LDS16(agp + (size_t)(i*32) * K + k0, &As[buf][i*2048 + tid*8]);
      GLOAD_LDS16(bgp + (size_t)(i*32) * K + k0, &Bs[buf][i*2048 + tid*8]);
    }
  };

  // prologue: tile 0 -> buf 0, full drain once
  STAGE(0, 0);
  __syncthreads();

  int cur = 0;
  for (int k0 = 0; k0 < K; k0 += 64) {
    if (k0 + 64 < K) STAGE(cur ^ 1, k0 + 64);   // prefetch next K-slice
    MEMBAR();                                    // pin issue point

    bf16x8 af[4][2], bfr[4][2];
#pragma unroll
    for (int i = 0; i < 4; ++i)
#pragma unroll
      for (int kk = 0; kk < 2; ++kk) {
        af[i][kk]  = *(const bf16x8*)(&As[cur][aro[i][kk]]);
        bfr[i][kk] = *(const bf16x8*)(&Bs[cur][bro[i][kk]]);
      }
#pragma unroll
    for (int kk = 0; kk < 2; ++kk)
#pragma unroll
      for (int mt = 0; mt < 4; ++mt)
#pragma unroll
        for (int nt = 0; nt < 4; ++nt)
          acc[mt][nt] = __builtin_amdgcn_mfma_f32_16x16x32_bf16(
              af[mt][kk], bfr[nt][kk], acc[mt][nt], 0, 0, 0);

    __syncthreads();   // drains prefetch (aged) + protects cur for rewrite
    cur ^= 1;
  }

#pragma unroll
  for (int nt = 0; nt < 4; ++nt) {
    const int n = n0 + wx*64 + nt*16 + col;
    const float bv = bias[n];
#pragma unroll
    for (int mt = 0; mt < 4; ++mt) {
#pragma unroll
      for (int r = 0; r < 4; ++r) {
        const int m = m0 + wy*64 + mt*16 + quad*4 + r;
        const float v = (acc[mt][nt][r] + bv) * oscale;
        if (OUT_BF16) ((u16*)Out)[(size_t)m * N + n] = f2bf(v);
        else          ((float*)Out)[(size_t)m * N + n] = v;
      }
    }
  }
}

// ---------------- V transpose: Vp[b,t,h,hd] -> Vt[b,h,hd,t] -------------------
__global__ __launch_bounds__(256) void transpose_v(
    const u16* __restrict__ Vp, u16* __restrict__ Vt) {
  const int blk = blockIdx.x;
  const int tt = blk & 31;
  const int bh = blk >> 5;
  const int b = bh >> 4, h = bh & 15;
  const int t0 = tt * 64;
  __shared__ u16 tile[64][66];
#pragma unroll
  for (int pass = 0; pass < 16; ++pass) {
    const int t = (threadIdx.x >> 6) + pass*4;
    const int d = threadIdx.x & 63;
    tile[t][d] = Vp[(size_t)(b*T_ + t0 + t) * D_ + h*HD_ + d];
  }
  __syncthreads();
#pragma unroll
  for (int pass = 0; pass < 16; ++pass) {
    const int d = (threadIdx.x >> 6) + pass*4;
    const int t = threadIdx.x & 63;
    Vt[(size_t)(bh*HD_ + d) * T_ + t0 + t] = tile[t][d];
  }
}

// ---------------- Flash attention: dbuf-staged K/V, 128-row q-blocks ----------
// (unchanged this round — VALU/TRANS-balanced; GEMM is the dominant cost)
__global__ __launch_bounds__(256) void attn_fwd(
    const u16* __restrict__ Qp, const u16* __restrict__ Kp,
    const u16* __restrict__ Vt, u16* __restrict__ Oout)
{
  __shared__ u16 Ks[2 * 4096];  // [buf][slot=hd/8][row=j][8]
  __shared__ u16 Vs[2 * 4096];  // [buf][slot=t/8][row=hd][8]
  __shared__ __align__(16) u16 plds[4 * 32 * 72];   // per-wave P, stride 72

  const int tid  = threadIdx.x;
  const int wave = tid >> 6;
  const int lane = tid & 63;
  const int col  = lane & 15;
  const int quad = lane >> 4;
  const int blk  = blockIdx.x;
  const int bh   = blk & 63;
  const int qt   = 15 - (blk >> 6);   // longest blocks first
  const int b = bh >> 4, h = bh & 15;
  const int rb0 = qt*128 + wave*16;   // group0 rows
  const int q0 = rb0 + col;
  const int q1 = q0 + 64;

  u16* const pl = plds + wave * 32 * 72;   // rows 0..15 grp0, 16..31 grp1

  // Q fragments (B-operand rows, k-contig; pre-scaled by SFC)
  bf16x8 qa0, qa1, qb0, qb1;
  {
    const u16* qr = Qp + (size_t)(b*T_ + q0) * D_ + h*HD_ + quad*8;
    qa0 = *(const bf16x8*)(qr);
    qa1 = *(const bf16x8*)(qr + 32);
    qr += (size_t)64 * D_;
    qb0 = *(const bf16x8*)(qr);
    qb1 = *(const bf16x8*)(qr + 32);
  }

  const u16* kbase = Kp + (size_t)(b*T_) * D_ + h*HD_;
  const u16* vbase = Vt + (size_t)(bh*HD_) * T_;

  const int srow  = tid & 63;
  const int sslot = tid >> 6;
  const u16* kg0 = kbase + (size_t)srow * D_ + sslot*8;
  const u16* kg1 = kbase + (size_t)srow * D_ + (4+sslot)*8;
  const u16* vg0 = vbase + (size_t)srow * T_ + sslot*8;
  const u16* vg1 = vbase + (size_t)srow * T_ + (4+sslot)*8;

  const f32x4 z = {0.f, 0.f, 0.f, 0.f};
  f32x4 oa[4], ob[4];
#pragma unroll
  for (int dt = 0; dt < 4; ++dt) { oa[dt] = z; ob[dt] = z; }
  f32x4 la = z, lb = z;

  const int jend0  = qt * 128;
  const int jend1  = qt * 128 + 64;
  const int ntiles = (jend1 >> 6) + 1;

  GLOAD_LDS16(kg0, Ks + tid*8);
  GLOAD_LDS16(kg1, Ks + 2048 + tid*8);
  GLOAD_LDS16(vg0, Vs + tid*8);
  GLOAD_LDS16(vg1, Vs + 2048 + tid*8);
  __syncthreads();

  int cur = 0;
  for (int t = 0; t < ntiles; ++t) {
    const int j0 = t << 6;

    if (t + 1 < ntiles) {
      const int jn = j0 + 64;
      const size_t kj = (size_t)jn * D_;
      u16* kb = Ks + (cur ^ 1) * 4096;
      u16* vb = Vs + (cur ^ 1) * 4096;
      GLOAD_LDS16(kg0 + kj, kb + tid*8);
      GLOAD_LDS16(kg1 + kj, kb + 2048 + tid*8);
      GLOAD_LDS16(vg0 + jn, vb + tid*8);
      GLOAD_LDS16(vg1 + jn, vb + 2048 + tid*8);
    }
    MEMBAR();

    const u16* kr = Ks + cur * 4096;
    const u16* vr = Vs + cur * 4096;

    f32x4 sa[4], sb[4];
    __builtin_amdgcn_s_setprio(1);
#pragma unroll
    for (int jt = 0; jt < 4; ++jt) {
      bf16x8 kf0 = *(const bf16x8*)(kr + (quad*64 + jt*16 + col) * 8);
      bf16x8 kf1 = *(const bf16x8*)(kr + 2048 + (quad*64 + jt*16 + col) * 8);
      sa[jt] = __builtin_amdgcn_mfma_f32_16x16x32_bf16(kf0, qa0, z, 0,0,0);
      sa[jt] = __builtin_amdgcn_mfma_f32_16x16x32_bf16(kf1, qa1, sa[jt], 0,0,0);
      sb[jt] = __builtin_amdgcn_mfma_f32_16x16x32_bf16(kf0, qb0, z, 0,0,0);
      sb[jt] = __builtin_amdgcn_mfma_f32_16x16x32_bf16(kf1, qb1, sb[jt], 0,0,0);
    }
    __builtin_amdgcn_s_setprio(0);

    if (j0 >= jend0) {
      const int dq = q0 - j0;
#pragma unroll
      for (int jt = 0; jt < 4; ++jt)
#pragma unroll
        for (int r = 0; r < 4; ++r) {
          const int jo = jt*16 + quad*4 + r;
          sa[jt][r] = (jo > dq) ? 0.f : __builtin_amdgcn_exp2f(sa[jt][r]);
        }
    } else {
#pragma unroll
      for (int jt = 0; jt < 4; ++jt)
#pragma unroll
        for (int r = 0; r < 4; ++r)
          sa[jt][r] = __builtin_amdgcn_exp2f(sa[jt][r]);
    }
    if (j0 >= jend1) {
      const int dq = q1 - j0;
#pragma unroll
      for (int jt = 0; jt < 4; ++jt)
#pragma unroll
        for (int r = 0; r < 4; ++r) {
          const int jo = jt*16 + quad*4 + r;
          sb[jt][r] = (jo > dq) ? 0.f : __builtin_amdgcn_exp2f(sb[jt][r]);
        }
    } else {
#pragma unroll
      for (int jt = 0; jt < 4; ++jt)
#pragma unroll
        for (int r = 0; r < 4; ++r)
          sb[jt][r] = __builtin_amdgcn_exp2f(sb[jt][r]);
    }
#pragma unroll
    for (int jt = 0; jt < 4; ++jt) { la += sa[jt]; lb += sb[jt]; }

    {
      u16* prow = pl + col * 72;
#pragma unroll
      for (int jt = 0; jt < 4; ++jt) {
        uint2 w2;
        w2.x = pack2bf(sa[jt][0], sa[jt][1]);
        w2.y = pack2bf(sa[jt][2], sa[jt][3]);
        *(uint2*)(prow + jt*16 + quad*4) = w2;
      }
      prow = pl + (16 + col) * 72;
#pragma unroll
      for (int jt = 0; jt < 4; ++jt) {
        uint2 w2;
        w2.x = pack2bf(sb[jt][0], sb[jt][1]);
        w2.y = pack2bf(sb[jt][2], sb[jt][3]);
        *(uint2*)(prow + jt*16 + quad*4) = w2;
      }
    }
    MEMBAR();

    {
      bf16x8 pa0 = *(const bf16x8*)(pl + col*72 + quad*8);
      bf16x8 pa1 = *(const bf16x8*)(pl + col*72 + 32 + quad*8);
      bf16x8 pb0 = *(const bf16x8*)(pl + (16+col)*72 + quad*8);
      bf16x8 pb1 = *(const bf16x8*)(pl + (16+col)*72 + 32 + quad*8);
      __builtin_amdgcn_s_setprio(1);
#pragma unroll
      for (int dt = 0; dt < 4; ++dt) {
        bf16x8 v0 = *(const bf16x8*)(vr + (quad*64 + dt*16 + col) * 8);
        bf16x8 v1 = *(const bf16x8*)(vr + 2048 + (quad*64 + dt*16 + col) * 8);
        oa[dt] = __builtin_amdgcn_mfma_f32_16x16x32_bf16(v0, pa0, oa[dt], 0,0,0);
        oa[dt] = __builtin_amdgcn_mfma_f32_16x16x32_bf16(v1, pa1, oa[dt], 0,0,0);
        ob[dt] = __builtin_amdgcn_mfma_f32_16x16x32_bf16(v0, pb0, ob[dt], 0,0,0);
        ob[dt] = __builtin_amdgcn_mfma_f32_16x16x32_bf16(v1, pb1, ob[dt], 0,0,0);
      }
      __builtin_amdgcn_s_setprio(0);
    }

    __syncthreads();
    cur ^= 1;
  }

  float l0 = (la[0] + la[1]) + (la[2] + la[3]);
  l0 += __shfl_xor(l0, 16);
  l0 += __shfl_xor(l0, 32);
  const float ra = __builtin_amdgcn_rcpf(l0);
  float l1 = (lb[0] + lb[1]) + (lb[2] + lb[3]);
  l1 += __shfl_xor(l1, 16);
  l1 += __shfl_xor(l1, 32);
  const float rb = __builtin_amdgcn_rcpf(l1);

  u16* orow = Oout + (size_t)(b*T_ + q0) * D_ + h*HD_;
#pragma unroll
  for (int dt = 0; dt < 4; ++dt) {
    uint2 w2;
    w2.x = pack2bf(oa[dt][0]*ra, oa[dt][1]*ra);
    w2.y = pack2bf(oa[dt][2]*ra, oa[dt][3]*ra);
    *(uint2*)(orow + dt*16 + quad*4) = w2;
  }
  orow += (size_t)64 * D_;
#pragma unroll
  for (int dt = 0; dt < 4; ++dt) {
    uint2 w2;
    w2.x = pack2bf(ob[dt][0]*rb, ob[dt][1]*rb);
    w2.y = pack2bf(ob[dt][2]*rb, ob[dt][3]*rb);
    *(uint2*)(orow + dt*16 + quad*4) = w2;
  }
}

// ------------------------------- launcher -------------------------------------
extern "C" void kernel_launch(void* const* d_in, const int* in_sizes, int n_in,
                              void* d_out, int out_size, void* d_ws, size_t ws_size,
                              hipStream_t stream) {
  const float* q  = (const float*)d_in[0];
  const float* k  = (const float*)d_in[1];
  const float* v  = (const float*)d_in[2];
  // d_in[3] = mask: causal tril, implemented analytically
  const float* Wq = (const float*)d_in[4];
  const float* bq = (const float*)d_in[5];
  const float* Wk = (const float*)d_in[6];
  const float* bk = (const float*)d_in[7];
  const float* Wv = (const float*)d_in[8];
  const float* bv = (const float*)d_in[9];
  const float* Wo = (const float*)d_in[10];
  const float* bo = (const float*)d_in[11];
  float* out = (float*)d_out;

  char* w = (char*)d_ws;
  const size_t SZ = (size_t)BT_ * D_ * sizeof(u16);   // 16 MiB per tensor
  u16* Qp = (u16*)(w + 0*SZ);
  u16* Kp = (u16*)(w + 1*SZ);
  u16* Vp = (u16*)(w + 2*SZ);
  u16* Vt = (u16*)(w + 3*SZ);
  u16* Xb = (u16*)(w + 4*SZ);   // bf16 input scratch; later attention output
  u16* Wb = (u16*)(w + 5*SZ);   // bf16 weight scratch (2 MiB)

  const int n4x = BT_ * D_ / 4;
  const int n4w = D_ * D_ / 4;
  const int cvx = n4x / 256, cvw = n4w / 256;
  const int gemm_g = (BT_/128) * (D_/128);       // 512 blocks (2/CU)
  const int tr_g   = (B_*H_) * (T_/64);          // 2048 blocks
  const int attn_g = (B_*H_) * (T_/128);         // 1024 blocks, longest-first
  dim3 blk(256);

  // Q projection (pre-scaled by SFC so attention scores exit in log2 units)
  cvt_f32_bf16<<<cvx, blk, 0, stream>>>(q,  Xb, n4x);
  cvt_f32_bf16<<<cvw, blk, 0, stream>>>(Wq, Wb, n4w);
  gemm_xwt_db<true><<<gemm_g, blk, 0, stream>>>(Xb, Wb, bq, Qp, BT_, D_, K_, SFC);
  // K projection
  cvt_f32_bf16<<<cvx, blk, 0, stream>>>(k,  Xb, n4x);
  cvt_f32_bf16<<<cvw, blk, 0, stream>>>(Wk, Wb, n4w);
  gemm_xwt_db<true><<<gemm_g, blk, 0, stream>>>(Xb, Wb, bk, Kp, BT_, D_, K_, 1.0f);
  // V projection
  cvt_f32_bf16<<<cvx, blk, 0, stream>>>(v,  Xb, n4x);
  cvt_f32_bf16<<<cvw, blk, 0, stream>>>(Wv, Wb, n4w);
  gemm_xwt_db<true><<<gemm_g, blk, 0, stream>>>(Xb, Wb, bv, Vp, BT_, D_, K_, 1.0f);
  // V transpose for PV operand layout
  transpose_v<<<tr_g, blk, 0, stream>>>(Vp, Vt);
  // attention (writes Xb)
  attn_fwd<<<attn_g, blk, 0, stream>>>(Qp, Kp, Vt, Xb);
  // output projection -> fp32 d_out
  cvt_f32_bf16<<<cvw, blk, 0, stream>>>(Wo, Wb, n4w);
  gemm_xwt_db<false><<<gemm_g, blk, 0, stream>>>(Xb, Wb, bo, (void*)out, BT_, D_, K_, 1.0f);
}

// Round 3
// 339.645 us; speedup vs baseline: 1.1557x; 1.0140x over previous
//
#include <hip/hip_runtime.h>

// Problem constants (B,T,D,H from reference)
#define B_  4
#define T_  2048
#define D_  1024
#define H_  16
#define HD_ 64
#define BT_ (B_*T_)   // 8192
#define K_  D_        // 1024 (GEMM inner dim)

typedef unsigned short u16;
typedef unsigned int   u32;

typedef __attribute__((ext_vector_type(8))) short bf16x8;  // 8 bf16 (4 VGPRs)
typedef __attribute__((ext_vector_type(4))) float f32x4;   // MFMA 16x16 C/D

__device__ __forceinline__ u16 f2bf(float f) {
  u32 u = __builtin_bit_cast(u32, f);
  u += 0x7fffu + ((u >> 16) & 1u);   // round-to-nearest-even
  return (u16)(u >> 16);
}

__device__ __forceinline__ u32 pack2bf(float a, float b) {
  u32 ua = __builtin_bit_cast(u32, a) + 0x8000u;
  u32 ub = __builtin_bit_cast(u32, b) + 0x8000u;
  return (ub & 0xFFFF0000u) | (ua >> 16);
}

#define GLOAD_LDS16(g, l) __builtin_amdgcn_global_load_lds(                  \
    (const __attribute__((address_space(1))) void*)(g),                      \
    (__attribute__((address_space(3))) void*)(l), 16, 0, 0)

// compiler-only memory barrier: forbids IR reordering of LDS/global ops
#define MEMBAR() __asm__ volatile("" ::: "memory")
#define SCHEDB() __builtin_amdgcn_sched_barrier(0)
#define SBAR()   __builtin_amdgcn_s_barrier()

#define SFC 0.18033688011f   /* 0.125 * log2(e); folded into Q projection */

// ---------------- fp32 -> bf16 elementwise convert (float4 -> 8B) -------------
__global__ __launch_bounds__(256) void cvt_f32_bf16(
    const float* __restrict__ in, u16* __restrict__ out, int n4) {
  int i = blockIdx.x * 256 + threadIdx.x;
  if (i >= n4) return;
  float4 x = ((const float4*)in)[i];
  u32 lo = (u32)f2bf(x.x) | ((u32)f2bf(x.y) << 16);
  u32 hi = (u32)f2bf(x.z) | ((u32)f2bf(x.w) << 16);
  ((uint2*)out)[i] = make_uint2(lo, hi);
}

// 3-tensor fused variant (q,k,v activations in one dispatch)
__global__ __launch_bounds__(256) void cvt3_f32_bf16(
    const float* __restrict__ i0, const float* __restrict__ i1,
    const float* __restrict__ i2,
    u16* __restrict__ o0, u16* __restrict__ o1, u16* __restrict__ o2,
    int cvx) {
  const int blk = blockIdx.x;
  const int seg = (blk >= 2*cvx) ? 2 : (blk >= cvx ? 1 : 0);
  const int ib  = blk - seg*cvx;
  const float* in = seg==0 ? i0 : (seg==1 ? i1 : i2);
  u16* out        = seg==0 ? o0 : (seg==1 ? o1 : o2);
  const int i = ib*256 + threadIdx.x;
  float4 x = ((const float4*)in)[i];
  u32 lo = (u32)f2bf(x.x) | ((u32)f2bf(x.y) << 16);
  u32 hi = (u32)f2bf(x.z) | ((u32)f2bf(x.w) << 16);
  ((uint2*)out)[i] = make_uint2(lo, hi);
}

// ---------------- GEMM: 128x128 tile, BK=32, counted-vmcnt pipeline -----------
// Out[m,n] = (A[m,:]·W[n,:] + bias[n]) * oscale.  4 waves 2x2 (each 64x64).
// QKV-fused: seg = blockIdx.x>>9 selects {A,W,bias,Out} (grid 1536 = 3x512);
// O-projection passes the same pointers 3x with grid 512.
// Pipeline (T4): STAGE(t+1) issues at top of iter t; then `s_waitcnt vmcnt(4)`
// (NOT 0 — the 4 in-flight loads are tile t+1's) guarantees tile t's loads
// landed; raw s_barrier publishes.  No vmcnt(0) drain in the main loop: loads
// age through a full compute phase + the other resident blocks' compute.
// 32KB LDS + launch_bounds(256,4) -> 4 blocks/CU.
// Slot swizzle: LDS row = 64B = 4 slots; physical slot s holds k-chunk
// s ^ ((row>>1)&3).  Frag ds_read_b128 bank-group = (row&1)*4 + slot -> per
// 16-lane quarter each 4-bank group serves exactly 2 lanes (optimal).
// MFMA operands SWAPPED (W-frag first): lane regs hold 4 consecutive n ->
// epilogue is 16 x 8B uint2 (bf16) or 16B float4 (fp32) stores, bias float4.
template<bool OUT_BF16>
__global__ __launch_bounds__(256, 4) void gemm_qkv(
    const u16* __restrict__ A0, const u16* __restrict__ A1,
    const u16* __restrict__ A2,
    const u16* __restrict__ W0, const u16* __restrict__ W1,
    const u16* __restrict__ W2,
    const float* __restrict__ b0, const float* __restrict__ b1,
    const float* __restrict__ b2,
    void* __restrict__ O0, void* __restrict__ O1, void* __restrict__ O2,
    float osc0)
{
  __shared__ u16 As[2][128 * 32];   // [buf][row][slot][8]
  __shared__ u16 Bs[2][128 * 32];

  const int tid  = threadIdx.x;
  const int wave = tid >> 6;
  const int lane = tid & 63;
  const int col  = lane & 15;
  const int quad = lane >> 4;
  const int wy   = wave >> 1;          // m-half (64)
  const int wx   = wave & 1;           // n-half (64)

  const int seg   = blockIdx.x >> 9;   // 0=Q 1=K 2=V (0 for O-proj)
  const int inner = blockIdx.x & 511;
  const u16*  A    = seg==0 ? A0 : (seg==1 ? A1 : A2);
  const u16*  W    = seg==0 ? W0 : (seg==1 ? W1 : W2);
  const float* bias = seg==0 ? b0 : (seg==1 ? b1 : b2);
  void*       Out  = seg==0 ? O0 : (seg==1 ? O1 : O2);
  const float oscale = (seg == 0) ? osc0 : 1.0f;

  // XCD-clustered swizzle within the 512-block segment: each XCD owns 8
  // m-panels x all 8 n-tiles -> A panels (2MiB) + W (2MiB) L2-resident.
  const int xcd = inner & 7;
  const int jj  = inner >> 3;          // 0..63
  const int m0 = (xcd*8 + (jj & 7)) * 128;
  const int n0 = (jj >> 3) * 128;

  // staging: 4 threads/row (64 rows/issue); physical slot tid&3 holds
  // k-chunk (tid&3) ^ ((row>>1)&3).  (row+64)>>1 keeps &3 -> same map both halves.
  const int srow = tid >> 2;                           // 0..63
  const int kseg = ((tid & 3) ^ ((srow >> 1) & 3)) * 8;
  const u16* agp = A + (size_t)(m0 + srow) * K_ + kseg;
  const u16* bgp = W + (size_t)(n0 + srow) * K_ + kseg;

  f32x4 acc[4][4];
  const f32x4 z = {0.f, 0.f, 0.f, 0.f};
#pragma unroll
  for (int i = 0; i < 4; ++i)
#pragma unroll
    for (int j = 0; j < 4; ++j) acc[i][j] = z;

  // frag LDS offsets (u16): row*32 + (quad ^ ((row>>1)&3))*8
  u32 aro[4], bro[4];
#pragma unroll
  for (int i = 0; i < 4; ++i) {
    const int ar = wy*64 + i*16 + col;
    const int br = wx*64 + i*16 + col;
    aro[i] = (u32)(ar*32 + ((quad ^ ((ar >> 1) & 3)) * 8));
    bro[i] = (u32)(br*32 + ((quad ^ ((br >> 1) & 3)) * 8));
  }

  auto STAGE = [&](int buf, int k0) {
    GLOAD_LDS16(agp + k0,               &As[buf][tid*8]);
    GLOAD_LDS16(agp + (size_t)64*K_ + k0, &As[buf][2048 + tid*8]);
    GLOAD_LDS16(bgp + k0,               &Bs[buf][tid*8]);
    GLOAD_LDS16(bgp + (size_t)64*K_ + k0, &Bs[buf][2048 + tid*8]);
  };

  STAGE(0, 0);
  MEMBAR();

  int cur = 0;
  for (int k0 = 0; k0 < K_; k0 += 32) {
    if (k0 + 32 < K_) {
      STAGE(cur ^ 1, k0 + 32);    // prefetch next K-slice (4 loads/wave)
      MEMBAR();
      __asm__ volatile("s_waitcnt vmcnt(4)" ::: "memory");  // tile t landed
    } else {
      __asm__ volatile("s_waitcnt vmcnt(0)" ::: "memory");  // last tile
    }
    SCHEDB();
    SBAR();            // publish: all waves' tile-t loads are in LDS
    MEMBAR();
    SCHEDB();

    bf16x8 af[4], bfr[4];
#pragma unroll
    for (int i = 0; i < 4; ++i) af[i]  = *(const bf16x8*)(&As[cur][aro[i]]);
#pragma unroll
    for (int i = 0; i < 4; ++i) bfr[i] = *(const bf16x8*)(&Bs[cur][bro[i]]);
    __asm__ volatile("s_waitcnt lgkmcnt(0)" ::: "memory");
    SCHEDB();
#pragma unroll
    for (int mt = 0; mt < 4; ++mt)
#pragma unroll
      for (int nt = 0; nt < 4; ++nt)
        acc[mt][nt] = __builtin_amdgcn_mfma_f32_16x16x32_bf16(
            bfr[nt], af[mt], acc[mt][nt], 0, 0, 0);   // swapped: regs = n-dim

    SCHEDB();
    SBAR();            // readers done -> buffer safe to restage next iter
    MEMBAR();
    SCHEDB();
    cur ^= 1;
  }

  // epilogue: lane holds 4 consecutive n per (mt,nt) -> vector stores
#pragma unroll
  for (int nt = 0; nt < 4; ++nt) {
    const int nb = n0 + wx*64 + nt*16 + quad*4;
    const float4 bv = *(const float4*)&bias[nb];
#pragma unroll
    for (int mt = 0; mt < 4; ++mt) {
      const int m = m0 + wy*64 + mt*16 + col;
      const float v0 = (acc[mt][nt][0] + bv.x) * oscale;
      const float v1 = (acc[mt][nt][1] + bv.y) * oscale;
      const float v2 = (acc[mt][nt][2] + bv.z) * oscale;
      const float v3 = (acc[mt][nt][3] + bv.w) * oscale;
      if (OUT_BF16) {
        uint2 w2 = make_uint2(pack2bf(v0, v1), pack2bf(v2, v3));
        *(uint2*)&((u16*)Out)[(size_t)m * D_ + nb] = w2;
      } else {
        float4 f4 = {v0, v1, v2, v3};
        *(float4*)&((float*)Out)[(size_t)m * D_ + nb] = f4;
      }
    }
  }
}

// ---------------- V transpose: Vp[b,t,h,hd] -> Vt[b,h,hd,t] -------------------
__global__ __launch_bounds__(256) void transpose_v(
    const u16* __restrict__ Vp, u16* __restrict__ Vt) {
  const int blk = blockIdx.x;
  const int tt = blk & 31;
  const int bh = blk >> 5;
  const int b = bh >> 4, h = bh & 15;
  const int t0 = tt * 64;
  __shared__ u16 tile[64][66];
#pragma unroll
  for (int pass = 0; pass < 16; ++pass) {
    const int t = (threadIdx.x >> 6) + pass*4;
    const int d = threadIdx.x & 63;
    tile[t][d] = Vp[(size_t)(b*T_ + t0 + t) * D_ + h*HD_ + d];
  }
  __syncthreads();
#pragma unroll
  for (int pass = 0; pass < 16; ++pass) {
    const int d = (threadIdx.x >> 6) + pass*4;
    const int t = threadIdx.x & 63;
    Vt[(size_t)(bh*HD_ + d) * T_ + t0 + t] = tile[t][d];
  }
}

// ---------------- Flash attention: dbuf-staged K/V, 128-row q-blocks ----------
// (frozen this round — GEMM is the dominant cost)
__global__ __launch_bounds__(256) void attn_fwd(
    const u16* __restrict__ Qp, const u16* __restrict__ Kp,
    const u16* __restrict__ Vt, u16* __restrict__ Oout)
{
  __shared__ u16 Ks[2 * 4096];  // [buf][slot=hd/8][row=j][8]
  __shared__ u16 Vs[2 * 4096];  // [buf][slot=t/8][row=hd][8]
  __shared__ __align__(16) u16 plds[4 * 32 * 72];   // per-wave P, stride 72

  const int tid  = threadIdx.x;
  const int wave = tid >> 6;
  const int lane = tid & 63;
  const int col  = lane & 15;
  const int quad = lane >> 4;
  const int blk  = blockIdx.x;
  const int bh   = blk & 63;
  const int qt   = 15 - (blk >> 6);   // longest blocks first
  const int b = bh >> 4, h = bh & 15;
  const int rb0 = qt*128 + wave*16;   // group0 rows
  const int q0 = rb0 + col;
  const int q1 = q0 + 64;

  u16* const pl = plds + wave * 32 * 72;   // rows 0..15 grp0, 16..31 grp1

  bf16x8 qa0, qa1, qb0, qb1;
  {
    const u16* qr = Qp + (size_t)(b*T_ + q0) * D_ + h*HD_ + quad*8;
    qa0 = *(const bf16x8*)(qr);
    qa1 = *(const bf16x8*)(qr + 32);
    qr += (size_t)64 * D_;
    qb0 = *(const bf16x8*)(qr);
    qb1 = *(const bf16x8*)(qr + 32);
  }

  const u16* kbase = Kp + (size_t)(b*T_) * D_ + h*HD_;
  const u16* vbase = Vt + (size_t)(bh*HD_) * T_;

  const int srow  = tid & 63;
  const int sslot = tid >> 6;
  const u16* kg0 = kbase + (size_t)srow * D_ + sslot*8;
  const u16* kg1 = kbase + (size_t)srow * D_ + (4+sslot)*8;
  const u16* vg0 = vbase + (size_t)srow * T_ + sslot*8;
  const u16* vg1 = vbase + (size_t)srow * T_ + (4+sslot)*8;

  const f32x4 z = {0.f, 0.f, 0.f, 0.f};
  f32x4 oa[4], ob[4];
#pragma unroll
  for (int dt = 0; dt < 4; ++dt) { oa[dt] = z; ob[dt] = z; }
  f32x4 la = z, lb = z;

  const int jend0  = qt * 128;
  const int jend1  = qt * 128 + 64;
  const int ntiles = (jend1 >> 6) + 1;

  GLOAD_LDS16(kg0, Ks + tid*8);
  GLOAD_LDS16(kg1, Ks + 2048 + tid*8);
  GLOAD_LDS16(vg0, Vs + tid*8);
  GLOAD_LDS16(vg1, Vs + 2048 + tid*8);
  __syncthreads();

  int cur = 0;
  for (int t = 0; t < ntiles; ++t) {
    const int j0 = t << 6;

    if (t + 1 < ntiles) {
      const int jn = j0 + 64;
      const size_t kj = (size_t)jn * D_;
      u16* kb = Ks + (cur ^ 1) * 4096;
      u16* vb = Vs + (cur ^ 1) * 4096;
      GLOAD_LDS16(kg0 + kj, kb + tid*8);
      GLOAD_LDS16(kg1 + kj, kb + 2048 + tid*8);
      GLOAD_LDS16(vg0 + jn, vb + tid*8);
      GLOAD_LDS16(vg1 + jn, vb + 2048 + tid*8);
    }
    MEMBAR();

    const u16* kr = Ks + cur * 4096;
    const u16* vr = Vs + cur * 4096;

    f32x4 sa[4], sb[4];
    __builtin_amdgcn_s_setprio(1);
#pragma unroll
    for (int jt = 0; jt < 4; ++jt) {
      bf16x8 kf0 = *(const bf16x8*)(kr + (quad*64 + jt*16 + col) * 8);
      bf16x8 kf1 = *(const bf16x8*)(kr + 2048 + (quad*64 + jt*16 + col) * 8);
      sa[jt] = __builtin_amdgcn_mfma_f32_16x16x32_bf16(kf0, qa0, z, 0,0,0);
      sa[jt] = __builtin_amdgcn_mfma_f32_16x16x32_bf16(kf1, qa1, sa[jt], 0,0,0);
      sb[jt] = __builtin_amdgcn_mfma_f32_16x16x32_bf16(kf0, qb0, z, 0,0,0);
      sb[jt] = __builtin_amdgcn_mfma_f32_16x16x32_bf16(kf1, qb1, sb[jt], 0,0,0);
    }
    __builtin_amdgcn_s_setprio(0);

    if (j0 >= jend0) {
      const int dq = q0 - j0;
#pragma unroll
      for (int jt = 0; jt < 4; ++jt)
#pragma unroll
        for (int r = 0; r < 4; ++r) {
          const int jo = jt*16 + quad*4 + r;
          sa[jt][r] = (jo > dq) ? 0.f : __builtin_amdgcn_exp2f(sa[jt][r]);
        }
    } else {
#pragma unroll
      for (int jt = 0; jt < 4; ++jt)
#pragma unroll
        for (int r = 0; r < 4; ++r)
          sa[jt][r] = __builtin_amdgcn_exp2f(sa[jt][r]);
    }
    if (j0 >= jend1) {
      const int dq = q1 - j0;
#pragma unroll
      for (int jt = 0; jt < 4; ++jt)
#pragma unroll
        for (int r = 0; r < 4; ++r) {
          const int jo = jt*16 + quad*4 + r;
          sb[jt][r] = (jo > dq) ? 0.f : __builtin_amdgcn_exp2f(sb[jt][r]);
        }
    } else {
#pragma unroll
      for (int jt = 0; jt < 4; ++jt)
#pragma unroll
        for (int r = 0; r < 4; ++r)
          sb[jt][r] = __builtin_amdgcn_exp2f(sb[jt][r]);
    }
#pragma unroll
    for (int jt = 0; jt < 4; ++jt) { la += sa[jt]; lb += sb[jt]; }

    {
      u16* prow = pl + col * 72;
#pragma unroll
      for (int jt = 0; jt < 4; ++jt) {
        uint2 w2;
        w2.x = pack2bf(sa[jt][0], sa[jt][1]);
        w2.y = pack2bf(sa[jt][2], sa[jt][3]);
        *(uint2*)(prow + jt*16 + quad*4) = w2;
      }
      prow = pl + (16 + col) * 72;
#pragma unroll
      for (int jt = 0; jt < 4; ++jt) {
        uint2 w2;
        w2.x = pack2bf(sb[jt][0], sb[jt][1]);
        w2.y = pack2bf(sb[jt][2], sb[jt][3]);
        *(uint2*)(prow + jt*16 + quad*4) = w2;
      }
    }
    MEMBAR();

    {
      bf16x8 pa0 = *(const bf16x8*)(pl + col*72 + quad*8);
      bf16x8 pa1 = *(const bf16x8*)(pl + col*72 + 32 + quad*8);
      bf16x8 pb0 = *(const bf16x8*)(pl + (16+col)*72 + quad*8);
      bf16x8 pb1 = *(const bf16x8*)(pl + (16+col)*72 + 32 + quad*8);
      __builtin_amdgcn_s_setprio(1);
#pragma unroll
      for (int dt = 0; dt < 4; ++dt) {
        bf16x8 v0 = *(const bf16x8*)(vr + (quad*64 + dt*16 + col) * 8);
        bf16x8 v1 = *(const bf16x8*)(vr + 2048 + (quad*64 + dt*16 + col) * 8);
        oa[dt] = __builtin_amdgcn_mfma_f32_16x16x32_bf16(v0, pa0, oa[dt], 0,0,0);
        oa[dt] = __builtin_amdgcn_mfma_f32_16x16x32_bf16(v1, pa1, oa[dt], 0,0,0);
        ob[dt] = __builtin_amdgcn_mfma_f32_16x16x32_bf16(v0, pb0, ob[dt], 0,0,0);
        ob[dt] = __builtin_amdgcn_mfma_f32_16x16x32_bf16(v1, pb1, ob[dt], 0,0,0);
      }
      __builtin_amdgcn_s_setprio(0);
    }

    __syncthreads();
    cur ^= 1;
  }

  float l0 = (la[0] + la[1]) + (la[2] + la[3]);
  l0 += __shfl_xor(l0, 16);
  l0 += __shfl_xor(l0, 32);
  const float ra = __builtin_amdgcn_rcpf(l0);
  float l1 = (lb[0] + lb[1]) + (lb[2] + lb[3]);
  l1 += __shfl_xor(l1, 16);
  l1 += __shfl_xor(l1, 32);
  const float rb = __builtin_amdgcn_rcpf(l1);

  u16* orow = Oout + (size_t)(b*T_ + q0) * D_ + h*HD_;
#pragma unroll
  for (int dt = 0; dt < 4; ++dt) {
    uint2 w2;
    w2.x = pack2bf(oa[dt][0]*ra, oa[dt][1]*ra);
    w2.y = pack2bf(oa[dt][2]*ra, oa[dt][3]*ra);
    *(uint2*)(orow + dt*16 + quad*4) = w2;
  }
  orow += (size_t)64 * D_;
#pragma unroll
  for (int dt = 0; dt < 4; ++dt) {
    uint2 w2;
    w2.x = pack2bf(ob[dt][0]*rb, ob[dt][1]*rb);
    w2.y = pack2bf(ob[dt][2]*rb, ob[dt][3]*rb);
    *(uint2*)(orow + dt*16 + quad*4) = w2;
  }
}

// ------------------------------- launcher -------------------------------------
extern "C" void kernel_launch(void* const* d_in, const int* in_sizes, int n_in,
                              void* d_out, int out_size, void* d_ws, size_t ws_size,
                              hipStream_t stream) {
  const float* q  = (const float*)d_in[0];
  const float* k  = (const float*)d_in[1];
  const float* v  = (const float*)d_in[2];
  // d_in[3] = mask: causal tril, implemented analytically
  const float* Wq = (const float*)d_in[4];
  const float* bq = (const float*)d_in[5];
  const float* Wk = (const float*)d_in[6];
  const float* bk = (const float*)d_in[7];
  const float* Wv = (const float*)d_in[8];
  const float* bv = (const float*)d_in[9];
  const float* Wo = (const float*)d_in[10];
  const float* bo = (const float*)d_in[11];
  float* out = (float*)d_out;

  char* w = (char*)d_ws;
  const size_t SZ = (size_t)BT_ * D_ * sizeof(u16);   // 16 MiB per tensor
  // workspace: 6x16 MiB + 3x2 MiB = 102 MiB
  u16* Xq = (u16*)(w + 0*SZ);
  u16* Xk = (u16*)(w + 1*SZ);
  u16* Xv = (u16*)(w + 2*SZ);
  u16* Qp = (u16*)(w + 3*SZ);
  u16* Kp = (u16*)(w + 4*SZ);
  u16* Vp = (u16*)(w + 5*SZ);
  u16* Wbq = (u16*)(w + 6*SZ);
  u16* Wbk = (u16*)(w + 6*SZ + (size_t)D_*D_*2);
  u16* Wbv = (u16*)(w + 6*SZ + (size_t)2*D_*D_*2);
  u16* Vt = Xk;   // free after gemm_qkv
  u16* AO = Xq;   // attention output; free after gemm_qkv

  const int n4x = BT_ * D_ / 4;
  const int n4w = D_ * D_ / 4;
  const int cvx = n4x / 256, cvw = n4w / 256;
  const int tr_g   = (B_*H_) * (T_/64);          // 2048 blocks
  const int attn_g = (B_*H_) * (T_/128);         // 1024 blocks, longest-first
  dim3 blk(256);

  // activation + weight converts (Q pre-scaled later via oscale in GEMM)
  cvt3_f32_bf16<<<3*cvx, blk, 0, stream>>>(q, k, v, Xq, Xk, Xv, cvx);
  cvt_f32_bf16<<<cvw, blk, 0, stream>>>(Wq, Wbq, n4w);
  cvt_f32_bf16<<<cvw, blk, 0, stream>>>(Wk, Wbk, n4w);
  cvt_f32_bf16<<<cvw, blk, 0, stream>>>(Wv, Wbv, n4w);

  // fused QKV projection (grid 1536 = 3 x 512)
  gemm_qkv<true><<<1536, blk, 0, stream>>>(
      Xq, Xk, Xv, Wbq, Wbk, Wbv, bq, bk, bv, Qp, Kp, Vp, SFC);

  // V transpose for PV operand layout
  transpose_v<<<tr_g, blk, 0, stream>>>(Vp, Vt);
  // attention
  attn_fwd<<<attn_g, blk, 0, stream>>>(Qp, Kp, Vt, AO);
  // output projection -> fp32 d_out
  cvt_f32_bf16<<<cvw, blk, 0, stream>>>(Wo, Wbq, n4w);
  gemm_qkv<false><<<512, blk, 0, stream>>>(
      AO, AO, AO, Wbq, Wbq, Wbq, bo, bo, bo, (void*)out, (void*)out,
      (void*)out, 1.0f);
}

// Round 4
// 330.554 us; speedup vs baseline: 1.1875x; 1.0275x over previous
//
#include <hip/hip_runtime.h>

// Problem constants (B,T,D,H from reference)
#define B_  4
#define T_  2048
#define D_  1024
#define H_  16
#define HD_ 64
#define BT_ (B_*T_)   // 8192
#define K_  D_        // 1024 (GEMM inner dim)

typedef unsigned short u16;
typedef unsigned int   u32;

typedef __attribute__((ext_vector_type(8))) short bf16x8;  // 8 bf16 (4 VGPRs)
typedef __attribute__((ext_vector_type(4))) float f32x4;   // MFMA 16x16 C/D

__device__ __forceinline__ u16 f2bf(float f) {
  u32 u = __builtin_bit_cast(u32, f);
  u += 0x7fffu + ((u >> 16) & 1u);   // round-to-nearest-even
  return (u16)(u >> 16);
}

__device__ __forceinline__ u32 pack2bf(float a, float b) {
  u32 ua = __builtin_bit_cast(u32, a) + 0x8000u;
  u32 ub = __builtin_bit_cast(u32, b) + 0x8000u;
  return (ub & 0xFFFF0000u) | (ua >> 16);
}

#define GLOAD_LDS16(g, l) __builtin_amdgcn_global_load_lds(                  \
    (const __attribute__((address_space(1))) void*)(g),                      \
    (__attribute__((address_space(3))) void*)(l), 16, 0, 0)

// compiler-only memory barrier: forbids IR reordering of LDS/global ops
#define MEMBAR() __asm__ volatile("" ::: "memory")
#define SCHEDB() __builtin_amdgcn_sched_barrier(0)
#define SBAR()   __builtin_amdgcn_s_barrier()

#define SFC 0.18033688011f   /* 0.125 * log2(e); folded into Q projection */

// ---------------- fp32 -> bf16 elementwise converts ---------------------------
__global__ __launch_bounds__(256) void cvt3_f32_bf16(
    const float* __restrict__ i0, const float* __restrict__ i1,
    const float* __restrict__ i2,
    u16* __restrict__ o0, u16* __restrict__ o1, u16* __restrict__ o2,
    int cvx) {
  const int blk = blockIdx.x;
  const int seg = (blk >= 2*cvx) ? 2 : (blk >= cvx ? 1 : 0);
  const int ib  = blk - seg*cvx;
  const float* in = seg==0 ? i0 : (seg==1 ? i1 : i2);
  u16* out        = seg==0 ? o0 : (seg==1 ? o1 : o2);
  const int i = ib*256 + threadIdx.x;
  float4 x = ((const float4*)in)[i];
  u32 lo = (u32)f2bf(x.x) | ((u32)f2bf(x.y) << 16);
  u32 hi = (u32)f2bf(x.z) | ((u32)f2bf(x.w) << 16);
  ((uint2*)out)[i] = make_uint2(lo, hi);
}

// all 4 weight matrices in one dispatch
__global__ __launch_bounds__(256) void cvt4_f32_bf16(
    const float* __restrict__ i0, const float* __restrict__ i1,
    const float* __restrict__ i2, const float* __restrict__ i3,
    u16* __restrict__ o0, u16* __restrict__ o1,
    u16* __restrict__ o2, u16* __restrict__ o3, int cvw) {
  const int blk = blockIdx.x;
  const int seg = blk / cvw;           // 0..3
  const int ib  = blk - seg*cvw;
  const float* in = seg==0 ? i0 : (seg==1 ? i1 : (seg==2 ? i2 : i3));
  u16* out        = seg==0 ? o0 : (seg==1 ? o1 : (seg==2 ? o2 : o3));
  const int i = ib*256 + threadIdx.x;
  float4 x = ((const float4*)in)[i];
  u32 lo = (u32)f2bf(x.x) | ((u32)f2bf(x.y) << 16);
  u32 hi = (u32)f2bf(x.z) | ((u32)f2bf(x.w) << 16);
  ((uint2*)out)[i] = make_uint2(lo, hi);
}

// ---------------- GEMM: 128x128 tile, BK=32, counted-vmcnt pipeline -----------
// QKV-fused: seg = blockIdx.x>>9 selects {A,W,bias,Out} (grid 1536 = 3x512).
// Pipeline (T4): STAGE(t+1) at top of iter t; `s_waitcnt vmcnt(4)` (never 0
// in-loop) guarantees tile t landed; raw s_barrier publishes.
// seg==2 (V projection) writes its output TRANSPOSED to Vt[b,h,hd,t] directly
// (replaces the standalone transpose_v kernel).  seg 0/1 write [b,t,h,hd].
__global__ __launch_bounds__(256, 4) void gemm_qkv(
    const u16* __restrict__ A0, const u16* __restrict__ A1,
    const u16* __restrict__ A2,
    const u16* __restrict__ W0, const u16* __restrict__ W1,
    const u16* __restrict__ W2,
    const float* __restrict__ b0, const float* __restrict__ b1,
    const float* __restrict__ b2,
    u16* __restrict__ O0, u16* __restrict__ O1, u16* __restrict__ O2,
    float osc0)
{
  __shared__ u16 As[2][128 * 32];   // [buf][row][slot][8]
  __shared__ u16 Bs[2][128 * 32];

  const int tid  = threadIdx.x;
  const int wave = tid >> 6;
  const int lane = tid & 63;
  const int col  = lane & 15;
  const int quad = lane >> 4;
  const int wy   = wave >> 1;          // m-half (64)
  const int wx   = wave & 1;           // n-half (64)

  const int seg   = blockIdx.x >> 9;   // 0=Q 1=K 2=V
  const int inner = blockIdx.x & 511;
  const u16*  A    = seg==0 ? A0 : (seg==1 ? A1 : A2);
  const u16*  W    = seg==0 ? W0 : (seg==1 ? W1 : W2);
  const float* bias = seg==0 ? b0 : (seg==1 ? b1 : b2);
  u16*        Out  = seg==0 ? O0 : (seg==1 ? O1 : O2);
  const float oscale = (seg == 0) ? osc0 : 1.0f;

  // XCD-clustered swizzle within the 512-block segment
  const int xcd = inner & 7;
  const int jj  = inner >> 3;          // 0..63
  const int m0 = (xcd*8 + (jj & 7)) * 128;
  const int n0 = (jj >> 3) * 128;

  // staging: 4 threads/row; physical slot tid&3 holds k-chunk (tid&3)^((row>>1)&3)
  const int srow = tid >> 2;                           // 0..63
  const int kseg = ((tid & 3) ^ ((srow >> 1) & 3)) * 8;
  const u16* agp = A + (size_t)(m0 + srow) * K_ + kseg;
  const u16* bgp = W + (size_t)(n0 + srow) * K_ + kseg;

  f32x4 acc[4][4];
  const f32x4 z = {0.f, 0.f, 0.f, 0.f};
#pragma unroll
  for (int i = 0; i < 4; ++i)
#pragma unroll
    for (int j = 0; j < 4; ++j) acc[i][j] = z;

  // frag LDS offsets (u16): row*32 + (quad ^ ((row>>1)&3))*8
  u32 aro[4], bro[4];
#pragma unroll
  for (int i = 0; i < 4; ++i) {
    const int ar = wy*64 + i*16 + col;
    const int br = wx*64 + i*16 + col;
    aro[i] = (u32)(ar*32 + ((quad ^ ((ar >> 1) & 3)) * 8));
    bro[i] = (u32)(br*32 + ((quad ^ ((br >> 1) & 3)) * 8));
  }

  auto STAGE = [&](int buf, int k0) {
    GLOAD_LDS16(agp + k0,                 &As[buf][tid*8]);
    GLOAD_LDS16(agp + (size_t)64*K_ + k0, &As[buf][2048 + tid*8]);
    GLOAD_LDS16(bgp + k0,                 &Bs[buf][tid*8]);
    GLOAD_LDS16(bgp + (size_t)64*K_ + k0, &Bs[buf][2048 + tid*8]);
  };

  STAGE(0, 0);
  MEMBAR();

  int cur = 0;
  for (int k0 = 0; k0 < K_; k0 += 32) {
    if (k0 + 32 < K_) {
      STAGE(cur ^ 1, k0 + 32);    // prefetch next K-slice (4 loads/wave)
      MEMBAR();
      __asm__ volatile("s_waitcnt vmcnt(4)" ::: "memory");  // tile t landed
    } else {
      __asm__ volatile("s_waitcnt vmcnt(0)" ::: "memory");  // last tile
    }
    SCHEDB();
    SBAR();            // publish: all waves' tile-t loads are in LDS
    MEMBAR();
    SCHEDB();

    bf16x8 af[4], bfr[4];
#pragma unroll
    for (int i = 0; i < 4; ++i) af[i]  = *(const bf16x8*)(&As[cur][aro[i]]);
#pragma unroll
    for (int i = 0; i < 4; ++i) bfr[i] = *(const bf16x8*)(&Bs[cur][bro[i]]);
    __asm__ volatile("s_waitcnt lgkmcnt(0)" ::: "memory");
    SCHEDB();
#pragma unroll
    for (int mt = 0; mt < 4; ++mt)
#pragma unroll
      for (int nt = 0; nt < 4; ++nt)
        acc[mt][nt] = __builtin_amdgcn_mfma_f32_16x16x32_bf16(
            bfr[nt], af[mt], acc[mt][nt], 0, 0, 0);   // swapped: regs = n-dim

    SCHEDB();
    SBAR();            // readers done -> buffer safe to restage next iter
    MEMBAR();
    SCHEDB();
    cur ^= 1;
  }

  // epilogue: lane holds 4 consecutive n per (mt,nt)
#pragma unroll
  for (int nt = 0; nt < 4; ++nt) {
    const int nb = n0 + wx*64 + nt*16 + quad*4;
    const float4 bv = *(const float4*)&bias[nb];
#pragma unroll
    for (int mt = 0; mt < 4; ++mt) {
      const int m = m0 + wy*64 + mt*16 + col;
      const float v0 = (acc[mt][nt][0] + bv.x) * oscale;
      const float v1 = (acc[mt][nt][1] + bv.y) * oscale;
      const float v2 = (acc[mt][nt][2] + bv.z) * oscale;
      const float v3 = (acc[mt][nt][3] + bv.w) * oscale;
      if (seg != 2) {
        uint2 w2 = make_uint2(pack2bf(v0, v1), pack2bf(v2, v3));
        *(uint2*)&Out[(size_t)m * D_ + nb] = w2;
      } else {
        // V: write transposed Vt[(b*16+h)*64+hd][t]; h=nb>>6, hd=nb&63,
        // t=m&2047, b=m>>11.  Lanes (col=t) are consecutive -> 32B runs.
        const int bb = m >> 11, t = m & 2047;
        const int h = nb >> 6, hd = nb & 63;
        u16* vp = Out + ((size_t)((bb*16 + h)*64 + hd)) * 2048 + t;
        vp[0]      = f2bf(v0);
        vp[2048]   = f2bf(v1);
        vp[4096]   = f2bf(v2);
        vp[6144]   = f2bf(v3);
      }
    }
  }
}

// ---------------- O-projection GEMM: 64x128 tile, grid 1024 -------------------
// Same counted-vmcnt pipeline; smaller m-tile doubles the block count so 4
// blocks/CU stay resident (the 512-block 128x128 version ran at 2/CU and was
// latency-bound).  4 waves of 32x64 (acc[2][4]); 3 staging issues per K-step
// (A 64x32 = 1 issue, B 128x32 = 2) -> in-loop wait is vmcnt(3).  24 KB LDS.
__global__ __launch_bounds__(256, 4) void gemm_o(
    const u16* __restrict__ A, const u16* __restrict__ W,
    const float* __restrict__ bias, float* __restrict__ Out)
{
  __shared__ u16 As[2][64 * 32];
  __shared__ u16 Bs[2][128 * 32];

  const int tid  = threadIdx.x;
  const int wave = tid >> 6;
  const int lane = tid & 63;
  const int col  = lane & 15;
  const int quad = lane >> 4;
  const int wy   = wave >> 1;          // m-half (32)
  const int wx   = wave & 1;           // n-half (64)

  // XCD-clustered: 1024 blocks; each XCD owns 16 m-panels x all 8 n-tiles
  const int xcd = blockIdx.x & 7;
  const int jj  = blockIdx.x >> 3;     // 0..127
  const int m0 = (xcd*16 + (jj & 15)) * 64;
  const int n0 = (jj >> 4) * 128;

  const int srow = tid >> 2;                           // 0..63
  const int kseg = ((tid & 3) ^ ((srow >> 1) & 3)) * 8;
  const u16* agp = A + (size_t)(m0 + srow) * K_ + kseg;
  const u16* bgp = W + (size_t)(n0 + srow) * K_ + kseg;

  f32x4 acc[2][4];
  const f32x4 z = {0.f, 0.f, 0.f, 0.f};
#pragma unroll
  for (int i = 0; i < 2; ++i)
#pragma unroll
    for (int j = 0; j < 4; ++j) acc[i][j] = z;

  u32 aro[2], bro[4];
#pragma unroll
  for (int i = 0; i < 2; ++i) {
    const int ar = wy*32 + i*16 + col;
    aro[i] = (u32)(ar*32 + ((quad ^ ((ar >> 1) & 3)) * 8));
  }
#pragma unroll
  for (int i = 0; i < 4; ++i) {
    const int br = wx*64 + i*16 + col;
    bro[i] = (u32)(br*32 + ((quad ^ ((br >> 1) & 3)) * 8));
  }

  auto STAGE = [&](int buf, int k0) {
    GLOAD_LDS16(agp + k0,                 &As[buf][tid*8]);
    GLOAD_LDS16(bgp + k0,                 &Bs[buf][tid*8]);
    GLOAD_LDS16(bgp + (size_t)64*K_ + k0, &Bs[buf][2048 + tid*8]);
  };

  STAGE(0, 0);
  MEMBAR();

  int cur = 0;
  for (int k0 = 0; k0 < K_; k0 += 32) {
    if (k0 + 32 < K_) {
      STAGE(cur ^ 1, k0 + 32);    // prefetch next K-slice (3 loads/wave)
      MEMBAR();
      __asm__ volatile("s_waitcnt vmcnt(3)" ::: "memory");
    } else {
      __asm__ volatile("s_waitcnt vmcnt(0)" ::: "memory");
    }
    SCHEDB();
    SBAR();
    MEMBAR();
    SCHEDB();

    bf16x8 af[2], bfr[4];
#pragma unroll
    for (int i = 0; i < 2; ++i) af[i]  = *(const bf16x8*)(&As[cur][aro[i]]);
#pragma unroll
    for (int i = 0; i < 4; ++i) bfr[i] = *(const bf16x8*)(&Bs[cur][bro[i]]);
    __asm__ volatile("s_waitcnt lgkmcnt(0)" ::: "memory");
    SCHEDB();
#pragma unroll
    for (int mt = 0; mt < 2; ++mt)
#pragma unroll
      for (int nt = 0; nt < 4; ++nt)
        acc[mt][nt] = __builtin_amdgcn_mfma_f32_16x16x32_bf16(
            bfr[nt], af[mt], acc[mt][nt], 0, 0, 0);

    SCHEDB();
    SBAR();
    MEMBAR();
    SCHEDB();
    cur ^= 1;
  }

#pragma unroll
  for (int nt = 0; nt < 4; ++nt) {
    const int nb = n0 + wx*64 + nt*16 + quad*4;
    const float4 bv = *(const float4*)&bias[nb];
#pragma unroll
    for (int mt = 0; mt < 2; ++mt) {
      const int m = m0 + wy*32 + mt*16 + col;
      float4 f4 = {acc[mt][nt][0] + bv.x, acc[mt][nt][1] + bv.y,
                   acc[mt][nt][2] + bv.z, acc[mt][nt][3] + bv.w};
      *(float4*)&Out[(size_t)m * D_ + nb] = f4;
    }
  }
}

// ---------------- Flash attention: dbuf-staged K/V, 128-row q-blocks ----------
// (frozen — control for this round)
__global__ __launch_bounds__(256) void attn_fwd(
    const u16* __restrict__ Qp, const u16* __restrict__ Kp,
    const u16* __restrict__ Vt, u16* __restrict__ Oout)
{
  __shared__ u16 Ks[2 * 4096];  // [buf][slot=hd/8][row=j][8]
  __shared__ u16 Vs[2 * 4096];  // [buf][slot=t/8][row=hd][8]
  __shared__ __align__(16) u16 plds[4 * 32 * 72];   // per-wave P, stride 72

  const int tid  = threadIdx.x;
  const int wave = tid >> 6;
  const int lane = tid & 63;
  const int col  = lane & 15;
  const int quad = lane >> 4;
  const int blk  = blockIdx.x;
  const int bh   = blk & 63;
  const int qt   = 15 - (blk >> 6);   // longest blocks first
  const int b = bh >> 4, h = bh & 15;
  const int rb0 = qt*128 + wave*16;   // group0 rows
  const int q0 = rb0 + col;
  const int q1 = q0 + 64;

  u16* const pl = plds + wave * 32 * 72;   // rows 0..15 grp0, 16..31 grp1

  bf16x8 qa0, qa1, qb0, qb1;
  {
    const u16* qr = Qp + (size_t)(b*T_ + q0) * D_ + h*HD_ + quad*8;
    qa0 = *(const bf16x8*)(qr);
    qa1 = *(const bf16x8*)(qr + 32);
    qr += (size_t)64 * D_;
    qb0 = *(const bf16x8*)(qr);
    qb1 = *(const bf16x8*)(qr + 32);
  }

  const u16* kbase = Kp + (size_t)(b*T_) * D_ + h*HD_;
  const u16* vbase = Vt + (size_t)(bh*HD_) * T_;

  const int srow  = tid & 63;
  const int sslot = tid >> 6;
  const u16* kg0 = kbase + (size_t)srow * D_ + sslot*8;
  const u16* kg1 = kbase + (size_t)srow * D_ + (4+sslot)*8;
  const u16* vg0 = vbase + (size_t)srow * T_ + sslot*8;
  const u16* vg1 = vbase + (size_t)srow * T_ + (4+sslot)*8;

  const f32x4 z = {0.f, 0.f, 0.f, 0.f};
  f32x4 oa[4], ob[4];
#pragma unroll
  for (int dt = 0; dt < 4; ++dt) { oa[dt] = z; ob[dt] = z; }
  f32x4 la = z, lb = z;

  const int jend0  = qt * 128;
  const int jend1  = qt * 128 + 64;
  const int ntiles = (jend1 >> 6) + 1;

  GLOAD_LDS16(kg0, Ks + tid*8);
  GLOAD_LDS16(kg1, Ks + 2048 + tid*8);
  GLOAD_LDS16(vg0, Vs + tid*8);
  GLOAD_LDS16(vg1, Vs + 2048 + tid*8);
  __syncthreads();

  int cur = 0;
  for (int t = 0; t < ntiles; ++t) {
    const int j0 = t << 6;

    if (t + 1 < ntiles) {
      const int jn = j0 + 64;
      const size_t kj = (size_t)jn * D_;
      u16* kb = Ks + (cur ^ 1) * 4096;
      u16* vb = Vs + (cur ^ 1) * 4096;
      GLOAD_LDS16(kg0 + kj, kb + tid*8);
      GLOAD_LDS16(kg1 + kj, kb + 2048 + tid*8);
      GLOAD_LDS16(vg0 + jn, vb + tid*8);
      GLOAD_LDS16(vg1 + jn, vb + 2048 + tid*8);
    }
    MEMBAR();

    const u16* kr = Ks + cur * 4096;
    const u16* vr = Vs + cur * 4096;

    f32x4 sa[4], sb[4];
    __builtin_amdgcn_s_setprio(1);
#pragma unroll
    for (int jt = 0; jt < 4; ++jt) {
      bf16x8 kf0 = *(const bf16x8*)(kr + (quad*64 + jt*16 + col) * 8);
      bf16x8 kf1 = *(const bf16x8*)(kr + 2048 + (quad*64 + jt*16 + col) * 8);
      sa[jt] = __builtin_amdgcn_mfma_f32_16x16x32_bf16(kf0, qa0, z, 0,0,0);
      sa[jt] = __builtin_amdgcn_mfma_f32_16x16x32_bf16(kf1, qa1, sa[jt], 0,0,0);
      sb[jt] = __builtin_amdgcn_mfma_f32_16x16x32_bf16(kf0, qb0, z, 0,0,0);
      sb[jt] = __builtin_amdgcn_mfma_f32_16x16x32_bf16(kf1, qb1, sb[jt], 0,0,0);
    }
    __builtin_amdgcn_s_setprio(0);

    if (j0 >= jend0) {
      const int dq = q0 - j0;
#pragma unroll
      for (int jt = 0; jt < 4; ++jt)
#pragma unroll
        for (int r = 0; r < 4; ++r) {
          const int jo = jt*16 + quad*4 + r;
          sa[jt][r] = (jo > dq) ? 0.f : __builtin_amdgcn_exp2f(sa[jt][r]);
        }
    } else {
#pragma unroll
      for (int jt = 0; jt < 4; ++jt)
#pragma unroll
        for (int r = 0; r < 4; ++r)
          sa[jt][r] = __builtin_amdgcn_exp2f(sa[jt][r]);
    }
    if (j0 >= jend1) {
      const int dq = q1 - j0;
#pragma unroll
      for (int jt = 0; jt < 4; ++jt)
#pragma unroll
        for (int r = 0; r < 4; ++r) {
          const int jo = jt*16 + quad*4 + r;
          sb[jt][r] = (jo > dq) ? 0.f : __builtin_amdgcn_exp2f(sb[jt][r]);
        }
    } else {
#pragma unroll
      for (int jt = 0; jt < 4; ++jt)
#pragma unroll
        for (int r = 0; r < 4; ++r)
          sb[jt][r] = __builtin_amdgcn_exp2f(sb[jt][r]);
    }
#pragma unroll
    for (int jt = 0; jt < 4; ++jt) { la += sa[jt]; lb += sb[jt]; }

    {
      u16* prow = pl + col * 72;
#pragma unroll
      for (int jt = 0; jt < 4; ++jt) {
        uint2 w2;
        w2.x = pack2bf(sa[jt][0], sa[jt][1]);
        w2.y = pack2bf(sa[jt][2], sa[jt][3]);
        *(uint2*)(prow + jt*16 + quad*4) = w2;
      }
      prow = pl + (16 + col) * 72;
#pragma unroll
      for (int jt = 0; jt < 4; ++jt) {
        uint2 w2;
        w2.x = pack2bf(sb[jt][0], sb[jt][1]);
        w2.y = pack2bf(sb[jt][2], sb[jt][3]);
        *(uint2*)(prow + jt*16 + quad*4) = w2;
      }
    }
    MEMBAR();

    {
      bf16x8 pa0 = *(const bf16x8*)(pl + col*72 + quad*8);
      bf16x8 pa1 = *(const bf16x8*)(pl + col*72 + 32 + quad*8);
      bf16x8 pb0 = *(const bf16x8*)(pl + (16+col)*72 + quad*8);
      bf16x8 pb1 = *(const bf16x8*)(pl + (16+col)*72 + 32 + quad*8);
      __builtin_amdgcn_s_setprio(1);
#pragma unroll
      for (int dt = 0; dt < 4; ++dt) {
        bf16x8 v0 = *(const bf16x8*)(vr + (quad*64 + dt*16 + col) * 8);
        bf16x8 v1 = *(const bf16x8*)(vr + 2048 + (quad*64 + dt*16 + col) * 8);
        oa[dt] = __builtin_amdgcn_mfma_f32_16x16x32_bf16(v0, pa0, oa[dt], 0,0,0);
        oa[dt] = __builtin_amdgcn_mfma_f32_16x16x32_bf16(v1, pa1, oa[dt], 0,0,0);
        ob[dt] = __builtin_amdgcn_mfma_f32_16x16x32_bf16(v0, pb0, ob[dt], 0,0,0);
        ob[dt] = __builtin_amdgcn_mfma_f32_16x16x32_bf16(v1, pb1, ob[dt], 0,0,0);
      }
      __builtin_amdgcn_s_setprio(0);
    }

    __syncthreads();
    cur ^= 1;
  }

  float l0 = (la[0] + la[1]) + (la[2] + la[3]);
  l0 += __shfl_xor(l0, 16);
  l0 += __shfl_xor(l0, 32);
  const float ra = __builtin_amdgcn_rcpf(l0);
  float l1 = (lb[0] + lb[1]) + (lb[2] + lb[3]);
  l1 += __shfl_xor(l1, 16);
  l1 += __shfl_xor(l1, 32);
  const float rb = __builtin_amdgcn_rcpf(l1);

  u16* orow = Oout + (size_t)(b*T_ + q0) * D_ + h*HD_;
#pragma unroll
  for (int dt = 0; dt < 4; ++dt) {
    uint2 w2;
    w2.x = pack2bf(oa[dt][0]*ra, oa[dt][1]*ra);
    w2.y = pack2bf(oa[dt][2]*ra, oa[dt][3]*ra);
    *(uint2*)(orow + dt*16 + quad*4) = w2;
  }
  orow += (size_t)64 * D_;
#pragma unroll
  for (int dt = 0; dt < 4; ++dt) {
    uint2 w2;
    w2.x = pack2bf(ob[dt][0]*rb, ob[dt][1]*rb);
    w2.y = pack2bf(ob[dt][2]*rb, ob[dt][3]*rb);
    *(uint2*)(orow + dt*16 + quad*4) = w2;
  }
}

// ------------------------------- launcher -------------------------------------
extern "C" void kernel_launch(void* const* d_in, const int* in_sizes, int n_in,
                              void* d_out, int out_size, void* d_ws, size_t ws_size,
                              hipStream_t stream) {
  const float* q  = (const float*)d_in[0];
  const float* k  = (const float*)d_in[1];
  const float* v  = (const float*)d_in[2];
  // d_in[3] = mask: causal tril, implemented analytically
  const float* Wq = (const float*)d_in[4];
  const float* bq = (const float*)d_in[5];
  const float* Wk = (const float*)d_in[6];
  const float* bk = (const float*)d_in[7];
  const float* Wv = (const float*)d_in[8];
  const float* bv = (const float*)d_in[9];
  const float* Wo = (const float*)d_in[10];
  const float* bo = (const float*)d_in[11];
  float* out = (float*)d_out;

  char* w = (char*)d_ws;
  const size_t SZ = (size_t)BT_ * D_ * sizeof(u16);   // 16 MiB per tensor
  // workspace: 6x16 MiB + 4x2 MiB = 104 MiB
  u16* Xq = (u16*)(w + 0*SZ);         // q-act bf16; later attention output
  u16* Xk = (u16*)(w + 1*SZ);
  u16* Xv = (u16*)(w + 2*SZ);
  u16* Qp = (u16*)(w + 3*SZ);
  u16* Kp = (u16*)(w + 4*SZ);
  u16* Vt = (u16*)(w + 5*SZ);         // written transposed by gemm_qkv seg 2
  u16* Wbq = (u16*)(w + 6*SZ);
  u16* Wbk = (u16*)(w + 6*SZ + 1*(size_t)D_*D_*2);
  u16* Wbv = (u16*)(w + 6*SZ + 2*(size_t)D_*D_*2);
  u16* Wbo = (u16*)(w + 6*SZ + 3*(size_t)D_*D_*2);
  u16* AO = Xq;

  const int n4x = BT_ * D_ / 4;
  const int n4w = D_ * D_ / 4;
  const int cvx = n4x / 256, cvw = n4w / 256;
  const int attn_g = (B_*H_) * (T_/128);         // 1024 blocks, longest-first
  dim3 blk(256);

  // converts: activations (1 dispatch) + all weights (1 dispatch)
  cvt3_f32_bf16<<<3*cvx, blk, 0, stream>>>(q, k, v, Xq, Xk, Xv, cvx);
  cvt4_f32_bf16<<<4*cvw, blk, 0, stream>>>(Wq, Wk, Wv, Wo,
                                           Wbq, Wbk, Wbv, Wbo, cvw);
  // fused QKV projection (V written pre-transposed)
  gemm_qkv<<<1536, blk, 0, stream>>>(
      Xq, Xk, Xv, Wbq, Wbk, Wbv, bq, bk, bv, Qp, Kp, Vt, SFC);
  // attention
  attn_fwd<<<attn_g, blk, 0, stream>>>(Qp, Kp, Vt, AO);
  // output projection -> fp32 d_out
  gemm_o<<<1024, blk, 0, stream>>>(AO, Wbo, bo, out);
}